// Round 10
// baseline (220.191 us; speedup 1.0000x reference)
//
#include <hip/hip_runtime.h>
#include <hip/hip_fp16.h>
#include <math.h>

// ---------------------------------------------------------------------------
// GCN. CSR build = bucketed counting sort, LDS atomics only (no global
// atomics: device-scope atomic-returns run memory-side at ~23 Gops/s on
// multi-XCD CDNA4 — measured R3/R4). ebuf packed (src<<9|local) in 4 B.
// Aggregation fused into the following GEMM (k_gmm): gather 64 node rows
// into LDS (fp32, bias+relu), then register-tiled GEMM from LDS. agg never
// touches HBM. t between layers is fp16.
// ---------------------------------------------------------------------------

#define TPB    256
#define EBLKS  256          // pass-1 edge blocks (256 -> all CUs busy)
#define BSH    9            // 512 nodes per bucket
#define BNODES (1 << BSH)

// P1a: OFS[c*EBLKS + b] = #edges of bucket c in block b's chunk
__global__ __launch_bounds__(TPB)
void k_p1hist(const int* __restrict__ dst, int* __restrict__ OFS,
              int E, int CH, int NBC) {
    __shared__ int h[512];
    int tid = threadIdx.x, b = blockIdx.x;
    for (int i = tid; i < NBC; i += TPB) h[i] = 0;
    __syncthreads();
    int beg = b * CH, end = min(E, beg + CH);
    if (beg < end) {
        int nfull = (end - beg) & ~3;
        for (int i = beg + tid * 4; i < beg + nfull; i += TPB * 4) {
            int4 d = *(const int4*)&dst[i];
            atomicAdd(&h[d.x >> BSH], 1);
            atomicAdd(&h[d.y >> BSH], 1);
            atomicAdd(&h[d.z >> BSH], 1);
            atomicAdd(&h[d.w >> BSH], 1);
        }
        if (tid < (end - beg) - nfull)
            atomicAdd(&h[dst[beg + nfull + tid] >> BSH], 1);
    }
    __syncthreads();
    for (int c = tid; c < NBC; c += TPB) OFS[c * EBLKS + b] = h[c];
}

// scanA: per-block sums (1024 elems/block) of OFS
__global__ __launch_bounds__(TPB)
void k_scanA(const int* __restrict__ OFS, int* __restrict__ bsum, int total) {
    __shared__ int s[TPB];
    int tid = threadIdx.x;
    int i0  = blockIdx.x * 1024 + tid * 4;
    int t = 0;
#pragma unroll
    for (int k = 0; k < 4; ++k) {
        int i = i0 + k;
        t += (i < total) ? OFS[i] : 0;
    }
    s[tid] = t;
    __syncthreads();
    for (int off = TPB / 2; off > 0; off >>= 1) {
        if (tid < off) s[tid] += s[tid + off];
        __syncthreads();
    }
    if (tid == 0) bsum[blockIdx.x] = s[0];
}

// scanC: exclusive scan; each block computes its own prefix over bsum
// via a masked 64-lane reduction (NBLK <= 64 for this problem size).
__global__ __launch_bounds__(TPB)
void k_scanC(int* __restrict__ OFS, const int* __restrict__ bsum,
             int NBLK, int total) {
    __shared__ int s[TPB];
    __shared__ int pfx;
    int tid = threadIdx.x;
    if (tid < 64) {
        int v = (tid < NBLK && tid < (int)blockIdx.x) ? bsum[tid] : 0;
#pragma unroll
        for (int off = 1; off < 64; off <<= 1) v += __shfl_xor(v, off);
        if (tid == 0) pfx = v;
    }
    int i0 = blockIdx.x * 1024 + tid * 4;
    int v[4];
#pragma unroll
    for (int k = 0; k < 4; ++k) {
        int i = i0 + k;
        v[k] = (i < total) ? OFS[i] : 0;
    }
    int tsum = v[0] + v[1] + v[2] + v[3];
    s[tid] = tsum;
    __syncthreads();
    for (int off = 1; off < TPB; off <<= 1) {
        int x = (tid >= off) ? s[tid - off] : 0;
        __syncthreads();
        s[tid] += x;
        __syncthreads();
    }
    int base = pfx + (s[tid] - tsum);
#pragma unroll
    for (int k = 0; k < 4; ++k) {
        int i = i0 + k;
        if (i < total) {
            OFS[i] = base;
            base += v[k];
        }
    }
}

// P1c: scatter packed (src<<9|local) into bucket-contiguous ebuf (LDS cursors)
__global__ __launch_bounds__(TPB)
void k_p1scatter(const int* __restrict__ src, const int* __restrict__ dst,
                 const int* __restrict__ OFS, int* __restrict__ ebuf,
                 int E, int CH, int NBC) {
    __shared__ int cur[512];
    int tid = threadIdx.x, b = blockIdx.x;
    for (int c = tid; c < NBC; c += TPB) cur[c] = OFS[c * EBLKS + b];
    __syncthreads();
    int beg = b * CH, end = min(E, beg + CH);
    if (beg >= end) return;
    int nfull = (end - beg) & ~3;
    for (int i = beg + tid * 4; i < beg + nfull; i += TPB * 4) {
        int4 s4 = *(const int4*)&src[i];
        int4 d4 = *(const int4*)&dst[i];
        int p0 = atomicAdd(&cur[d4.x >> BSH], 1);
        int p1 = atomicAdd(&cur[d4.y >> BSH], 1);
        int p2 = atomicAdd(&cur[d4.z >> BSH], 1);
        int p3 = atomicAdd(&cur[d4.w >> BSH], 1);
        ebuf[p0] = (s4.x << BSH) | (d4.x & (BNODES - 1));
        ebuf[p1] = (s4.y << BSH) | (d4.y & (BNODES - 1));
        ebuf[p2] = (s4.z << BSH) | (d4.z & (BNODES - 1));
        ebuf[p3] = (s4.w << BSH) | (d4.w & (BNODES - 1));
    }
    if (tid < (end - beg) - nfull) {
        int i = beg + nfull + tid;
        int d = dst[i];
        int p = atomicAdd(&cur[d >> BSH], 1);
        ebuf[p] = (src[i] << BSH) | (d & (BNODES - 1));
    }
}

// P2a: per bucket: LDS hist over 512 local nodes -> scan -> row_ptr, dinv
__global__ __launch_bounds__(TPB)
void k_p2rowptr(const int* __restrict__ ebuf, const int* __restrict__ OFS,
                int* __restrict__ row_ptr, float* __restrict__ dinv,
                int N, int E, int NBC) {
    __shared__ int cnt[BNODES];
    __shared__ int s1[TPB];
    int tid = threadIdx.x, c = blockIdx.x;
    int beg = OFS[c * EBLKS];
    int end = (c == NBC - 1) ? E : OFS[(c + 1) * EBLKS];
    for (int i = tid; i < BNODES; i += TPB) cnt[i] = 0;
    __syncthreads();
    for (int i = beg + tid; i < end; i += TPB)
        atomicAdd(&cnt[ebuf[i] & (BNODES - 1)], 1);
    __syncthreads();
    int a0 = cnt[2 * tid], a1 = cnt[2 * tid + 1];
    int pairsum = a0 + a1;
    s1[tid] = pairsum;
    __syncthreads();
    for (int off = 1; off < TPB; off <<= 1) {
        int x = (tid >= off) ? s1[tid - off] : 0;
        __syncthreads();
        s1[tid] += x;
        __syncthreads();
    }
    int ex = s1[tid] - pairsum;
    int node0 = (c << BSH) + 2 * tid;
    if (node0 < N) {
        row_ptr[node0] = beg + ex;
        dinv[node0]    = rsqrtf((float)(a0 + 1));
    }
    if (node0 + 1 < N) {
        row_ptr[node0 + 1] = beg + ex + a0;
        dinv[node0 + 1]    = rsqrtf((float)(a1 + 1));
    }
    if (c == NBC - 1 && tid == 0) row_ptr[N] = E;
}

// P2b: per bucket: LDS rank -> colw[row_ptr[d]+rank] = {src, dinv[s]*dinv[d]}
__global__ __launch_bounds__(TPB)
void k_p2fill(const int* __restrict__ ebuf, const int* __restrict__ OFS,
              const int* __restrict__ row_ptr, const float* __restrict__ dinv,
              int2* __restrict__ colw, int E, int NBC) {
    __shared__ int cnt[BNODES];
    int tid = threadIdx.x, c = blockIdx.x;
    int beg = OFS[c * EBLKS];
    int end = (c == NBC - 1) ? E : OFS[(c + 1) * EBLKS];
    int cbase = c << BSH;
    for (int i = tid; i < BNODES; i += TPB) cnt[i] = 0;
    __syncthreads();
    for (int i0 = beg + tid; i0 < end; i0 += TPB * 4) {
        int   sv[4], dl[4], pos[4];
        float w[4];
        int   have = 0;
#pragma unroll
        for (int k = 0; k < 4; ++k) {
            int i = i0 + k * TPB;
            if (i < end) {
                int e = ebuf[i];
                sv[k] = e >> BSH;
                dl[k] = e & (BNODES - 1);
                have = k + 1;
            }
        }
#pragma unroll
        for (int k = 0; k < 4; ++k) {
            if (k < have) {
                int r  = atomicAdd(&cnt[dl[k]], 1);
                pos[k] = row_ptr[cbase + dl[k]] + r;
                w[k]   = dinv[sv[k]] * dinv[cbase + dl[k]];
            }
        }
#pragma unroll
        for (int k = 0; k < 4; ++k)
            if (k < have) colw[pos[k]] = make_int2(sv[k], __float_as_int(w[k]));
    }
}

// Layer-1 GEMM: [n,64] fp32 @ [64,64] -> t fp16 (no bias).
__launch_bounds__(256)
__global__ void k_mm1(const float* __restrict__ in, const float* __restrict__ W,
                      __half* __restrict__ t_out, int n) {
    __shared__ float in_s[64 * 68];
    __shared__ float w_s[64 * 64];

    const int tid  = threadIdx.x;
    const int row0 = blockIdx.x * 64;

    for (int i4 = tid; i4 < (64 * 64) / 4; i4 += 256)
        ((float4*)w_s)[i4] = ((const float4*)W)[i4];

    for (int idx = tid; idx < 64 * 16; idx += 256) {
        int r  = idx >> 4;
        int c4 = idx & 15;
        float4 v;
        if (row0 + r < n)
            v = *(const float4*)&in[(size_t)(row0 + r) * 64 + c4 * 4];
        else
            v = make_float4(0.f, 0.f, 0.f, 0.f);
        *(float4*)&in_s[r * 68 + c4 * 4] = v;
    }
    __syncthreads();

    const int tx = tid & 15;
    const int ty = tid >> 4;

    float acc[4][4];
#pragma unroll
    for (int r = 0; r < 4; ++r)
#pragma unroll
        for (int c = 0; c < 4; ++c) acc[r][c] = 0.f;

#pragma unroll 4
    for (int k = 0; k < 64; ++k) {
        float b[4];
#pragma unroll
        for (int c = 0; c < 4; ++c) b[c] = w_s[k * 64 + tx * 4 + c];
#pragma unroll
        for (int r = 0; r < 4; ++r) {
            float a = in_s[(ty * 4 + r) * 68 + k];
#pragma unroll
            for (int c = 0; c < 4; ++c) acc[r][c] = fmaf(a, b[c], acc[r][c]);
        }
    }

#pragma unroll
    for (int r = 0; r < 4; ++r) {
        int row = row0 + ty * 4 + r;
        if (row >= n) continue;
        __half2 p0 = __floats2half2_rn(acc[r][0], acc[r][1]);
        __half2 p1 = __floats2half2_rn(acc[r][2], acc[r][3]);
        uint2 u = make_uint2(*(unsigned*)&p0, *(unsigned*)&p1);
        *(uint2*)(t_out + (size_t)row * 64 + tx * 4) = u;
    }
}

// Fused gather + GEMM. Phase 1: gather this block's 64 node rows
// (agg = relu(gbias + dinv^2*t[d] + sum w_e t[src])) into in_s (fp32).
// 8 lanes/node, 8 nodes/wave, 2 rounds. Phase 2: register-tiled GEMM.
// FINAL: out fp32 += fbias. Else: out fp16 (next layer's t).
template <int F, bool FINAL>
__launch_bounds__(256)
__global__ void k_gmm(const int* __restrict__ row_ptr, const int2* __restrict__ colw,
                      const float* __restrict__ dinv, const float* __restrict__ gbias,
                      const __half* __restrict__ t, const float* __restrict__ W,
                      const float* __restrict__ fbias, void* __restrict__ out, int n) {
    __shared__ float in_s[64 * 68];
    __shared__ float w_s[64 * F];

    const int tid  = threadIdx.x;
    const int row0 = blockIdx.x * 64;

    for (int i4 = tid; i4 < (64 * F) / 4; i4 += 256)
        ((float4*)w_s)[i4] = ((const float4*)W)[i4];

    // --- gather phase ---
    const int wv   = tid >> 6;
    const int lane = tid & 63;
    const int g    = lane >> 3;
    const int p    = lane & 7;
    float4 gb0 = *(const float4*)&gbias[p * 8];
    float4 gb1 = *(const float4*)&gbias[p * 8 + 4];

#pragma unroll
    for (int round = 0; round < 2; ++round) {
        int m = round * 32 + wv * 8 + g;
        int d = row0 + m;
        float acc[8];
#pragma unroll
        for (int k = 0; k < 8; ++k) acc[k] = 0.f;
        float o[8];
        if (d < n) {
            int beg = row_ptr[d], end = row_ptr[d + 1];
            for (int e = beg; e < end; e += 2) {
                int2 cw0 = colw[e];
                int2 cw1 = (e + 1 < end) ? colw[e + 1] : make_int2(0, 0);
                uint4 a0 = *(const uint4*)(t + (size_t)cw0.x * 64 + p * 8);
                uint4 a1 = *(const uint4*)(t + (size_t)cw1.x * 64 + p * 8);
                float w0 = __int_as_float(cw0.y);
                float w1 = __int_as_float(cw1.y);
                float2 f;
                f = __half22float2(*(__half2*)&a0.x); acc[0] = fmaf(w0, f.x, acc[0]); acc[1] = fmaf(w0, f.y, acc[1]);
                f = __half22float2(*(__half2*)&a0.y); acc[2] = fmaf(w0, f.x, acc[2]); acc[3] = fmaf(w0, f.y, acc[3]);
                f = __half22float2(*(__half2*)&a0.z); acc[4] = fmaf(w0, f.x, acc[4]); acc[5] = fmaf(w0, f.y, acc[5]);
                f = __half22float2(*(__half2*)&a0.w); acc[6] = fmaf(w0, f.x, acc[6]); acc[7] = fmaf(w0, f.y, acc[7]);
                f = __half22float2(*(__half2*)&a1.x); acc[0] = fmaf(w1, f.x, acc[0]); acc[1] = fmaf(w1, f.y, acc[1]);
                f = __half22float2(*(__half2*)&a1.y); acc[2] = fmaf(w1, f.x, acc[2]); acc[3] = fmaf(w1, f.y, acc[3]);
                f = __half22float2(*(__half2*)&a1.z); acc[4] = fmaf(w1, f.x, acc[4]); acc[5] = fmaf(w1, f.y, acc[5]);
                f = __half22float2(*(__half2*)&a1.w); acc[6] = fmaf(w1, f.x, acc[6]); acc[7] = fmaf(w1, f.y, acc[7]);
            }
            float dd = dinv[d];
            float w2 = dd * dd;
            uint4 a = *(const uint4*)(t + (size_t)d * 64 + p * 8);
            float2 s0 = __half22float2(*(__half2*)&a.x);
            float2 s1 = __half22float2(*(__half2*)&a.y);
            float2 s2 = __half22float2(*(__half2*)&a.z);
            float2 s3 = __half22float2(*(__half2*)&a.w);
            o[0] = fmaxf(fmaf(w2, s0.x, acc[0]) + gb0.x, 0.f);
            o[1] = fmaxf(fmaf(w2, s0.y, acc[1]) + gb0.y, 0.f);
            o[2] = fmaxf(fmaf(w2, s1.x, acc[2]) + gb0.z, 0.f);
            o[3] = fmaxf(fmaf(w2, s1.y, acc[3]) + gb0.w, 0.f);
            o[4] = fmaxf(fmaf(w2, s2.x, acc[4]) + gb1.x, 0.f);
            o[5] = fmaxf(fmaf(w2, s2.y, acc[5]) + gb1.y, 0.f);
            o[6] = fmaxf(fmaf(w2, s3.x, acc[6]) + gb1.z, 0.f);
            o[7] = fmaxf(fmaf(w2, s3.y, acc[7]) + gb1.w, 0.f);
        } else {
#pragma unroll
            for (int k = 0; k < 8; ++k) o[k] = 0.f;
        }
        float* ls = &in_s[m * 68 + p * 8];
        *(float4*)&ls[0] = make_float4(o[0], o[1], o[2], o[3]);
        *(float4*)&ls[4] = make_float4(o[4], o[5], o[6], o[7]);
    }
    __syncthreads();

    // --- GEMM phase ---
    constexpr int CPT = F / 16;
    const int tx = tid & 15;
    const int ty = tid >> 4;

    float acc[4][CPT];
#pragma unroll
    for (int r = 0; r < 4; ++r)
#pragma unroll
        for (int c = 0; c < CPT; ++c) acc[r][c] = 0.f;

#pragma unroll 4
    for (int k = 0; k < 64; ++k) {
        float b[CPT];
#pragma unroll
        for (int c = 0; c < CPT; ++c) b[c] = w_s[k * F + tx * CPT + c];
#pragma unroll
        for (int r = 0; r < 4; ++r) {
            float a = in_s[(ty * 4 + r) * 68 + k];
#pragma unroll
            for (int c = 0; c < CPT; ++c) acc[r][c] = fmaf(a, b[c], acc[r][c]);
        }
    }

#pragma unroll
    for (int r = 0; r < 4; ++r) {
        int row = row0 + ty * 4 + r;
        if (row >= n) continue;
        if constexpr (FINAL) {
#pragma unroll
            for (int c = 0; c < CPT; ++c) {
                int col = tx * CPT + c;
                ((float*)out)[(size_t)row * F + col] = acc[r][c] + fbias[col];
            }
        } else {
            __half2 p0 = __floats2half2_rn(acc[r][0], acc[r][1]);
            __half2 p1 = __floats2half2_rn(acc[r][2], acc[r][3]);
            uint2 u = make_uint2(*(unsigned*)&p0, *(unsigned*)&p1);
            *(uint2*)((__half*)out + (size_t)row * 64 + tx * 4) = u;
        }
    }
}

extern "C" void kernel_launch(void* const* d_in, const int* in_sizes, int n_in,
                              void* d_out, int out_size, void* d_ws, size_t ws_size,
                              hipStream_t stream) {
    const float* x  = (const float*)d_in[0];
    const int*   ei = (const int*)d_in[1];
    const float* W1 = (const float*)d_in[2];
    const float* b1 = (const float*)d_in[3];
    const float* W2 = (const float*)d_in[4];
    const float* b2 = (const float*)d_in[5];
    const float* Wl = (const float*)d_in[6];
    const float* bl = (const float*)d_in[7];
    float*       out = (float*)d_out;

    const int N = in_sizes[0] / 64;
    const int E = in_sizes[1] / 2;
    const int* srcp = ei;
    const int* dstp = ei + E;

    const int NBC   = (N + BNODES - 1) / BNODES;             // buckets
    const int CH    = (((E + EBLKS - 1) / EBLKS) + 3) & ~3;  // chunk, mult of 4
    const int total = NBC * EBLKS;                           // offset matrix
    const int NBLK  = (total + 1023) / 1024;                 // scan blocks (<=64)

    char*  ws  = (char*)d_ws;
    size_t off = 0;
    auto alloc = [&](size_t bytes) -> void* {
        void* p = (void*)(ws + off);
        off += (bytes + 255) & ~(size_t)255;
        return p;
    };
    int*    OFS     = (int*)alloc(((size_t)total + 1) * 4);
    int*    bsum    = (int*)alloc((size_t)NBLK * 4);
    int*    ebuf    = (int*)alloc((size_t)E * 4);
    int*    row_ptr = (int*)alloc((size_t)(N + 1) * 4);
    float*  dinv    = (float*)alloc((size_t)N * 4);
    int2*   colw    = (int2*)alloc((size_t)E * 8);
    __half* t1      = (__half*)alloc((size_t)N * 64 * 2);
    __half* t2      = (__half*)alloc((size_t)N * 64 * 2);

    const int nb_mm = (N + 63) / 64;

    // --- CSR build (no global atomics) ---
    k_p1hist   <<<EBLKS, TPB, 0, stream>>>(dstp, OFS, E, CH, NBC);
    k_scanA    <<<NBLK,  TPB, 0, stream>>>(OFS, bsum, total);
    k_scanC    <<<NBLK,  TPB, 0, stream>>>(OFS, bsum, NBLK, total);
    k_p1scatter<<<EBLKS, TPB, 0, stream>>>(srcp, dstp, OFS, ebuf, E, CH, NBC);
    k_p2rowptr <<<NBC,   TPB, 0, stream>>>(ebuf, OFS, row_ptr, dinv, N, E, NBC);
    k_p2fill   <<<NBC,   TPB, 0, stream>>>(ebuf, OFS, row_ptr, dinv, colw, E, NBC);

    // --- layer 1 GEMM ---
    k_mm1<<<nb_mm, 256, 0, stream>>>(x, W1, t1, N);

    // --- gather1 + layer 2 GEMM (fused) ---
    k_gmm<64, false><<<nb_mm, 256, 0, stream>>>(row_ptr, colw, dinv, b1, t1,
                                                W2, nullptr, t2, N);

    // --- gather2 + head (fused) ---
    k_gmm<32, true><<<nb_mm, 256, 0, stream>>>(row_ptr, colw, dinv, b2, t2,
                                               Wl, bl, out, N);
}

// Round 11
// 209.674 us; speedup vs baseline: 1.0502x; 1.0502x over previous
//
#include <hip/hip_runtime.h>
#include <hip/hip_fp16.h>
#include <math.h>

// ---------------------------------------------------------------------------
// GCN. CSR build = bucketed counting sort, LDS atomics only (no global
// atomics: device-scope atomic-returns run memory-side at ~23 Gops/s on
// multi-XCD CDNA4 — measured R3/R4). ebuf packed (src<<9|local) in 4 B.
// Algebraic refactor: t' = dinv[row] * (row @ W)  (scaled in mm epilogue) so
//   agg[d] = relu(b + dinv[d] * (sum_e t'[src_e] + t'[d]))
// -> colw stores ONLY src (4 B), gather inner loop is pure adds, and the
// p2 rank/fill pass needs no dinv -> fused with rowptr into one kernel.
// Gather: 8 nodes/wave, 8 lanes/node, sentinel zero-row N for tail edges.
// Fusing gather into the GEMM was tried (R10) and regressed: 33 KB LDS
// halves occupancy for the latency-bound gather phase. Keep them split.
// ---------------------------------------------------------------------------

#define TPB    256
#define EBLKS  256          // pass-1 edge blocks (256 -> all CUs busy)
#define BSH    9            // 512 nodes per bucket
#define BNODES (1 << BSH)

// P1a: OFS[c*EBLKS + b] = #edges of bucket c in block b's chunk
__global__ __launch_bounds__(TPB)
void k_p1hist(const int* __restrict__ dst, int* __restrict__ OFS,
              int E, int CH, int NBC) {
    __shared__ int h[512];
    int tid = threadIdx.x, b = blockIdx.x;
    for (int i = tid; i < NBC; i += TPB) h[i] = 0;
    __syncthreads();
    int beg = b * CH, end = min(E, beg + CH);
    if (beg < end) {
        int nfull = (end - beg) & ~3;
        for (int i = beg + tid * 4; i < beg + nfull; i += TPB * 4) {
            int4 d = *(const int4*)&dst[i];
            atomicAdd(&h[d.x >> BSH], 1);
            atomicAdd(&h[d.y >> BSH], 1);
            atomicAdd(&h[d.z >> BSH], 1);
            atomicAdd(&h[d.w >> BSH], 1);
        }
        if (tid < (end - beg) - nfull)
            atomicAdd(&h[dst[beg + nfull + tid] >> BSH], 1);
    }
    __syncthreads();
    for (int c = tid; c < NBC; c += TPB) OFS[c * EBLKS + b] = h[c];
}

// scanA: per-block sums (1024 elems/block) of OFS
__global__ __launch_bounds__(TPB)
void k_scanA(const int* __restrict__ OFS, int* __restrict__ bsum, int total) {
    __shared__ int s[TPB];
    int tid = threadIdx.x;
    int i0  = blockIdx.x * 1024 + tid * 4;
    int t = 0;
#pragma unroll
    for (int k = 0; k < 4; ++k) {
        int i = i0 + k;
        t += (i < total) ? OFS[i] : 0;
    }
    s[tid] = t;
    __syncthreads();
    for (int off = TPB / 2; off > 0; off >>= 1) {
        if (tid < off) s[tid] += s[tid + off];
        __syncthreads();
    }
    if (tid == 0) bsum[blockIdx.x] = s[0];
}

// scanC: exclusive scan; each block computes its own prefix over bsum
// via a masked 64-lane reduction (NBLK <= 64 here).
__global__ __launch_bounds__(TPB)
void k_scanC(int* __restrict__ OFS, const int* __restrict__ bsum,
             int NBLK, int total) {
    __shared__ int s[TPB];
    __shared__ int pfx;
    int tid = threadIdx.x;
    if (tid < 64) {
        int v = (tid < NBLK && tid < (int)blockIdx.x) ? bsum[tid] : 0;
#pragma unroll
        for (int off = 1; off < 64; off <<= 1) v += __shfl_xor(v, off);
        if (tid == 0) pfx = v;
    }
    int i0 = blockIdx.x * 1024 + tid * 4;
    int v[4];
#pragma unroll
    for (int k = 0; k < 4; ++k) {
        int i = i0 + k;
        v[k] = (i < total) ? OFS[i] : 0;
    }
    int tsum = v[0] + v[1] + v[2] + v[3];
    s[tid] = tsum;
    __syncthreads();
    for (int off = 1; off < TPB; off <<= 1) {
        int x = (tid >= off) ? s[tid - off] : 0;
        __syncthreads();
        s[tid] += x;
        __syncthreads();
    }
    int base = pfx + (s[tid] - tsum);
#pragma unroll
    for (int k = 0; k < 4; ++k) {
        int i = i0 + k;
        if (i < total) {
            OFS[i] = base;
            base += v[k];
        }
    }
}

// P1c: scatter packed (src<<9|local) into bucket-contiguous ebuf (LDS cursors)
__global__ __launch_bounds__(TPB)
void k_p1scatter(const int* __restrict__ src, const int* __restrict__ dst,
                 const int* __restrict__ OFS, int* __restrict__ ebuf,
                 int E, int CH, int NBC) {
    __shared__ int cur[512];
    int tid = threadIdx.x, b = blockIdx.x;
    for (int c = tid; c < NBC; c += TPB) cur[c] = OFS[c * EBLKS + b];
    __syncthreads();
    int beg = b * CH, end = min(E, beg + CH);
    if (beg >= end) return;
    int nfull = (end - beg) & ~3;
    for (int i = beg + tid * 4; i < beg + nfull; i += TPB * 4) {
        int4 s4 = *(const int4*)&src[i];
        int4 d4 = *(const int4*)&dst[i];
        int p0 = atomicAdd(&cur[d4.x >> BSH], 1);
        int p1 = atomicAdd(&cur[d4.y >> BSH], 1);
        int p2 = atomicAdd(&cur[d4.z >> BSH], 1);
        int p3 = atomicAdd(&cur[d4.w >> BSH], 1);
        ebuf[p0] = (s4.x << BSH) | (d4.x & (BNODES - 1));
        ebuf[p1] = (s4.y << BSH) | (d4.y & (BNODES - 1));
        ebuf[p2] = (s4.z << BSH) | (d4.z & (BNODES - 1));
        ebuf[p3] = (s4.w << BSH) | (d4.w & (BNODES - 1));
    }
    if (tid < (end - beg) - nfull) {
        int i = beg + nfull + tid;
        int d = dst[i];
        int p = atomicAdd(&cur[d >> BSH], 1);
        ebuf[p] = (src[i] << BSH) | (d & (BNODES - 1));
    }
}

// P2 (fused): per bucket: LDS hist over 512 local nodes -> scan ->
// row_ptr/dinv + LDS start offsets; then rank pass -> colw[ofs+rank] = src.
// No dinv reads (weights deferred to t' scaling) -> no cross-bucket race.
__global__ __launch_bounds__(TPB)
void k_p2(const int* __restrict__ ebuf, const int* __restrict__ OFS,
          int* __restrict__ row_ptr, float* __restrict__ dinv,
          int* __restrict__ colw, int N, int E, int NBC) {
    __shared__ int cnt[BNODES];
    __shared__ int ofs[BNODES];
    __shared__ int s1[TPB];
    int tid = threadIdx.x, c = blockIdx.x;
    int beg = OFS[c * EBLKS];
    int end = (c == NBC - 1) ? E : OFS[(c + 1) * EBLKS];
    for (int i = tid; i < BNODES; i += TPB) cnt[i] = 0;
    __syncthreads();
    for (int i = beg + tid; i < end; i += TPB)
        atomicAdd(&cnt[ebuf[i] & (BNODES - 1)], 1);
    __syncthreads();
    int a0 = cnt[2 * tid], a1 = cnt[2 * tid + 1];
    int pairsum = a0 + a1;
    s1[tid] = pairsum;
    __syncthreads();
    for (int off = 1; off < TPB; off <<= 1) {
        int x = (tid >= off) ? s1[tid - off] : 0;
        __syncthreads();
        s1[tid] += x;
        __syncthreads();
    }
    int ex = s1[tid] - pairsum;
    int node0 = (c << BSH) + 2 * tid;
    ofs[2 * tid]     = beg + ex;
    ofs[2 * tid + 1] = beg + ex + a0;
    if (node0 < N) {
        row_ptr[node0] = beg + ex;
        dinv[node0]    = rsqrtf((float)(a0 + 1));
    }
    if (node0 + 1 < N) {
        row_ptr[node0 + 1] = beg + ex + a0;
        dinv[node0 + 1]    = rsqrtf((float)(a1 + 1));
    }
    if (c == NBC - 1 && tid == 0) row_ptr[N] = E;
    cnt[2 * tid] = 0;
    cnt[2 * tid + 1] = 0;
    __syncthreads();
    // rank + fill (colw = src only)
    for (int i0 = beg + tid; i0 < end; i0 += TPB * 4) {
        int sv[4], dl[4], pos[4];
        int have = 0;
#pragma unroll
        for (int k = 0; k < 4; ++k) {
            int i = i0 + k * TPB;
            if (i < end) {
                int e = ebuf[i];
                sv[k] = e >> BSH;
                dl[k] = e & (BNODES - 1);
                have = k + 1;
            }
        }
#pragma unroll
        for (int k = 0; k < 4; ++k) {
            if (k < have) {
                int r  = atomicAdd(&cnt[dl[k]], 1);
                pos[k] = ofs[dl[k]] + r;
            }
        }
#pragma unroll
        for (int k = 0; k < 4; ++k)
            if (k < have) colw[pos[k]] = sv[k];
    }
}

// Dense GEMM: [n,64] @ [64,F].
// !FINAL: out = fp16 t' = dinv[row]*(row@W); also writes zero sentinel row n.
// FINAL:  out = fp32 row@W + bias.
// HIN: input rows fp16, else fp32.
template <int F, bool FINAL, bool HIN>
__launch_bounds__(256)
__global__ void k_mm(const void* __restrict__ in, const float* __restrict__ W,
                     const float* __restrict__ bias, const float* __restrict__ dinv,
                     void* __restrict__ out, int n) {
    __shared__ float in_s[64 * 68];
    __shared__ float w_s[64 * F];

    const int tid  = threadIdx.x;
    const int row0 = blockIdx.x * 64;

    for (int i4 = tid; i4 < (64 * F) / 4; i4 += 256)
        ((float4*)w_s)[i4] = ((const float4*)W)[i4];

    if constexpr (HIN) {
        for (int idx = tid; idx < 64 * 8; idx += 256) {
            int r  = idx >> 3;
            int c8 = idx & 7;
            uint4 u = make_uint4(0u, 0u, 0u, 0u);
            if (row0 + r < n)
                u = *(const uint4*)((const __half*)in + (size_t)(row0 + r) * 64 + c8 * 8);
            float2 f0 = __half22float2(*(__half2*)&u.x);
            float2 f1 = __half22float2(*(__half2*)&u.y);
            float2 f2 = __half22float2(*(__half2*)&u.z);
            float2 f3 = __half22float2(*(__half2*)&u.w);
            float* o = &in_s[r * 68 + c8 * 8];
            *(float4*)&o[0] = make_float4(f0.x, f0.y, f1.x, f1.y);
            *(float4*)&o[4] = make_float4(f2.x, f2.y, f3.x, f3.y);
        }
    } else {
        for (int idx = tid; idx < 64 * 16; idx += 256) {
            int r  = idx >> 4;
            int c4 = idx & 15;
            float4 v;
            if (row0 + r < n)
                v = *(const float4*)((const float*)in + (size_t)(row0 + r) * 64 + c4 * 4);
            else
                v = make_float4(0.f, 0.f, 0.f, 0.f);
            *(float4*)&in_s[r * 68 + c4 * 4] = v;
        }
    }
    __syncthreads();

    constexpr int CPT = F / 16;
    const int tx = tid & 15;
    const int ty = tid >> 4;

    float acc[4][CPT];
#pragma unroll
    for (int r = 0; r < 4; ++r)
#pragma unroll
        for (int c = 0; c < CPT; ++c) acc[r][c] = 0.f;

#pragma unroll 4
    for (int k = 0; k < 64; ++k) {
        float b[CPT];
#pragma unroll
        for (int c = 0; c < CPT; ++c) b[c] = w_s[k * F + tx * CPT + c];
#pragma unroll
        for (int r = 0; r < 4; ++r) {
            float a = in_s[(ty * 4 + r) * 68 + k];
#pragma unroll
            for (int c = 0; c < CPT; ++c) acc[r][c] = fmaf(a, b[c], acc[r][c]);
        }
    }

#pragma unroll
    for (int r = 0; r < 4; ++r) {
        int row = row0 + ty * 4 + r;
        if (row >= n) continue;
        if constexpr (FINAL) {
#pragma unroll
            for (int c = 0; c < CPT; ++c) {
                int col = tx * CPT + c;
                ((float*)out)[(size_t)row * F + col] = acc[r][c] + bias[col];
            }
        } else {
            float dd = dinv[row];
            __half2 p0 = __floats2half2_rn(acc[r][0] * dd, acc[r][1] * dd);
            __half2 p1 = __floats2half2_rn(acc[r][2] * dd, acc[r][3] * dd);
            uint2 u = make_uint2(*(unsigned*)&p0, *(unsigned*)&p1);
            *(uint2*)((__half*)out + (size_t)row * 64 + tx * 4) = u;
        }
    }
    if constexpr (!FINAL) {
        // zero sentinel row n (tail edges in gather read it)
        if (blockIdx.x == 0 && tid < 16)
            *(uint2*)((__half*)out + (size_t)n * 64 + tid * 4) = make_uint2(0u, 0u);
    }
}

// Gather: 8 nodes/wave, 8 lanes/node, no weights (t' pre-scaled):
// agg[d] = relu(bias + dinv[d] * (sum_e t'[src_e] + t'[d])), fp16 out.
__global__ __launch_bounds__(256)
void k_gather(const int* __restrict__ row_ptr, const int* __restrict__ colw,
              const float* __restrict__ dinv, const float* __restrict__ bias,
              const __half* __restrict__ t, __half* __restrict__ agg, int N) {
    int tid  = threadIdx.x;
    int wv   = tid >> 6;
    int lane = tid & 63;
    int g = lane >> 3;
    int p = lane & 7;
    int d = blockIdx.x * 32 + wv * 8 + g;

    int beg = 0, end = 0;
    if (d < N) { beg = row_ptr[d]; end = row_ptr[d + 1]; }

    float acc[8];
#pragma unroll
    for (int k = 0; k < 8; ++k) acc[k] = 0.f;

    for (int e = beg; e < end; e += 2) {
        int s0 = colw[e];
        int s1 = (e + 1 < end) ? colw[e + 1] : N;   // N = zero sentinel row
        uint4 a0 = *(const uint4*)(t + (size_t)s0 * 64 + p * 8);
        uint4 a1 = *(const uint4*)(t + (size_t)s1 * 64 + p * 8);
        float2 f;
        f = __half22float2(*(__half2*)&a0.x); acc[0] += f.x; acc[1] += f.y;
        f = __half22float2(*(__half2*)&a0.y); acc[2] += f.x; acc[3] += f.y;
        f = __half22float2(*(__half2*)&a0.z); acc[4] += f.x; acc[5] += f.y;
        f = __half22float2(*(__half2*)&a0.w); acc[6] += f.x; acc[7] += f.y;
        f = __half22float2(*(__half2*)&a1.x); acc[0] += f.x; acc[1] += f.y;
        f = __half22float2(*(__half2*)&a1.y); acc[2] += f.x; acc[3] += f.y;
        f = __half22float2(*(__half2*)&a1.z); acc[4] += f.x; acc[5] += f.y;
        f = __half22float2(*(__half2*)&a1.w); acc[6] += f.x; acc[7] += f.y;
    }

    if (d < N) {
        float dd = dinv[d];
        uint4 a = *(const uint4*)(t + (size_t)d * 64 + p * 8);
        float4 b0 = *(const float4*)&bias[p * 8];
        float4 b1 = *(const float4*)&bias[p * 8 + 4];
        float2 s0 = __half22float2(*(__half2*)&a.x);
        float2 s1 = __half22float2(*(__half2*)&a.y);
        float2 s2 = __half22float2(*(__half2*)&a.z);
        float2 s3 = __half22float2(*(__half2*)&a.w);
        float o0 = fmaxf(fmaf(dd, acc[0] + s0.x, b0.x), 0.f);
        float o1 = fmaxf(fmaf(dd, acc[1] + s0.y, b0.y), 0.f);
        float o2 = fmaxf(fmaf(dd, acc[2] + s1.x, b0.z), 0.f);
        float o3 = fmaxf(fmaf(dd, acc[3] + s1.y, b0.w), 0.f);
        float o4 = fmaxf(fmaf(dd, acc[4] + s2.x, b1.x), 0.f);
        float o5 = fmaxf(fmaf(dd, acc[5] + s2.y, b1.y), 0.f);
        float o6 = fmaxf(fmaf(dd, acc[6] + s3.x, b1.z), 0.f);
        float o7 = fmaxf(fmaf(dd, acc[7] + s3.y, b1.w), 0.f);
        __half2 h0 = __floats2half2_rn(o0, o1);
        __half2 h1 = __floats2half2_rn(o2, o3);
        __half2 h2 = __floats2half2_rn(o4, o5);
        __half2 h3 = __floats2half2_rn(o6, o7);
        uint4 u = make_uint4(*(unsigned*)&h0, *(unsigned*)&h1,
                             *(unsigned*)&h2, *(unsigned*)&h3);
        *(uint4*)(agg + (size_t)d * 64 + p * 8) = u;
    }
}

extern "C" void kernel_launch(void* const* d_in, const int* in_sizes, int n_in,
                              void* d_out, int out_size, void* d_ws, size_t ws_size,
                              hipStream_t stream) {
    const float* x  = (const float*)d_in[0];
    const int*   ei = (const int*)d_in[1];
    const float* W1 = (const float*)d_in[2];
    const float* b1 = (const float*)d_in[3];
    const float* W2 = (const float*)d_in[4];
    const float* b2 = (const float*)d_in[5];
    const float* Wl = (const float*)d_in[6];
    const float* bl = (const float*)d_in[7];
    float*       out = (float*)d_out;

    const int N = in_sizes[0] / 64;
    const int E = in_sizes[1] / 2;
    const int* srcp = ei;
    const int* dstp = ei + E;

    const int NBC   = (N + BNODES - 1) / BNODES;             // buckets
    const int CH    = (((E + EBLKS - 1) / EBLKS) + 3) & ~3;  // chunk, mult of 4
    const int total = NBC * EBLKS;                           // offset matrix
    const int NBLK  = (total + 1023) / 1024;                 // scan blocks (<=64)

    char*  ws  = (char*)d_ws;
    size_t off = 0;
    auto alloc = [&](size_t bytes) -> void* {
        void* p = (void*)(ws + off);
        off += (bytes + 255) & ~(size_t)255;
        return p;
    };
    int*    OFS     = (int*)alloc(((size_t)total + 1) * 4);
    int*    bsum    = (int*)alloc((size_t)NBLK * 4);
    int*    ebuf    = (int*)alloc((size_t)E * 4);
    int*    row_ptr = (int*)alloc((size_t)(N + 1) * 4);
    float*  dinv    = (float*)alloc((size_t)N * 4);
    int*    colw    = (int*)alloc((size_t)E * 4);
    __half* t1      = (__half*)alloc((size_t)(N + 1) * 64 * 2);  // +sentinel
    __half* agg1    = (__half*)alloc((size_t)N * 64 * 2);
    __half* t2      = t1;    // safe: t1 dead once gather1 consumed it
    __half* agg2    = agg1;  // safe: agg1 dead once mm2 wrote t2

    const int nb_mm = (N + 63) / 64;
    const int nb_g  = (N + 31) / 32;

    // --- CSR build (no global atomics) ---
    k_p1hist   <<<EBLKS, TPB, 0, stream>>>(dstp, OFS, E, CH, NBC);
    k_scanA    <<<NBLK,  TPB, 0, stream>>>(OFS, bsum, total);
    k_scanC    <<<NBLK,  TPB, 0, stream>>>(OFS, bsum, NBLK, total);
    k_p1scatter<<<EBLKS, TPB, 0, stream>>>(srcp, dstp, OFS, ebuf, E, CH, NBC);
    k_p2       <<<NBC,   TPB, 0, stream>>>(ebuf, OFS, row_ptr, dinv, colw, N, E, NBC);

    // --- layer 1: t1' = dinv * (x @ W1) ---
    k_mm<64, false, false><<<nb_mm, 256, 0, stream>>>(x, W1, nullptr, dinv, t1, N);
    k_gather<<<nb_g, 256, 0, stream>>>(row_ptr, colw, dinv, b1, t1, agg1, N);

    // --- layer 2: t2' = dinv * (agg1 @ W2) ---
    k_mm<64, false, true><<<nb_mm, 256, 0, stream>>>(agg1, W2, nullptr, dinv, t2, N);
    k_gather<<<nb_g, 256, 0, stream>>>(row_ptr, colw, dinv, b2, t2, agg2, N);

    // --- head ---
    k_mm<32, true, true><<<nb_mm, 256, 0, stream>>>(agg2, Wl, bl, nullptr, out, N);
}